// Round 8
// baseline (508.661 us; speedup 1.0000x reference)
//
#include <hip/hip_runtime.h>
#include <hip/hip_bf16.h>
#include <stdint.h>

#define C_DIM 768
#define HW 16384
#define EPSF 1e-8f
#define GPP 128            // groups (16 cols) per partition (8 partitions)

typedef __attribute__((ext_vector_type(4))) int i32x4;

// ---------------- Kernel A: per-channel means over spatial dim ----------------
__global__ __launch_bounds__(256) void k_means(const float* __restrict__ x,
                                               const float* __restrict__ s,
                                               float* __restrict__ meanA,
                                               float* __restrict__ meanB) {
  int ch = blockIdx.x;
  const float* src = (ch < C_DIM) ? (x + (size_t)ch * HW) : (s + (size_t)(ch - C_DIM) * HW);
  const float4* src4 = (const float4*)src;
  int t = threadIdx.x;
  float acc = 0.f;
  for (int i = t; i < HW / 4; i += 256) {
    float4 v = src4[i];
    acc += v.x + v.y + v.z + v.w;
  }
  __shared__ float red[256];
  red[t] = acc;
  __syncthreads();
  for (int o = 128; o > 0; o >>= 1) {
    if (t < o) red[t] += red[t + o];
    __syncthreads();
  }
  if (t == 0) {
    float m = red[0] * (1.0f / HW);
    if (ch < C_DIM) meanA[ch] = m; else meanB[ch - C_DIM] = m;
  }
}

// ---------------- Kernel P: fused stats + quantize + pack ----------------
__global__ __launch_bounds__(256) void k_prepq(const float* __restrict__ x,
                                               const float* __restrict__ s,
                                               const float* __restrict__ meanA,
                                               const float* __restrict__ meanB,
                                               float* __restrict__ qsaG,
                                               float* __restrict__ effG,
                                               float* __restrict__ invbnG,
                                               float* __restrict__ rawNA,
                                               float* __restrict__ rawNB,
                                               float* __restrict__ uG,
                                               float* __restrict__ vG,
                                               signed char* __restrict__ qa,
                                               signed char* __restrict__ Bp) {
  __shared__ float lma[C_DIM], lmb[C_DIM];
  __shared__ float red[7 * 256];
  __shared__ signed char tA8[64 * 40];
  __shared__ signed char tB8[64 * 40];
  __shared__ float lsa[64], lsb[64];
  int t = threadIdx.x;
  int j0 = blockIdx.x * 64;
  for (int c = t; c < C_DIM; c += 256) { lma[c] = meanA[c]; lmb[c] = meanB[c]; }
  __syncthreads();

  // ---- phase 1: stats ----
  {
    int pl = t & 63, cl = t >> 6;
    int p = j0 + pl;
    float maxa = 0.f, ssaR = 0.f, maxb = 0.f, ssbC = 0.f, ssbR = 0.f, uacc = 0.f, vacc = 0.f;
    for (int c = cl; c < C_DIM; c += 4) {
      float av = x[(size_t)c * HW + p];
      float bv = s[(size_t)c * HW + p];
      float ac = av - lma[c];
      float bc = bv - lmb[c];
      maxa = fmaxf(maxa, fabsf(ac));
      maxb = fmaxf(maxb, fabsf(bc));
      ssaR += av * av;
      ssbC += bc * bc;
      ssbR += bv * bv;
      uacc += ac * lmb[c];
      vacc += bc * lma[c];
    }
    red[t] = maxa; red[256 + t] = ssaR; red[512 + t] = maxb;
    red[768 + t] = ssbC; red[1024 + t] = ssbR; red[1280 + t] = uacc; red[1536 + t] = vacc;
    __syncthreads();
    if (t < 64) {
      float ma = fmaxf(fmaxf(red[t], red[t + 64]), fmaxf(red[t + 128], red[t + 192]));
      float sa = red[256 + t] + red[256 + t + 64] + red[256 + t + 128] + red[256 + t + 192];
      float mb = fmaxf(fmaxf(red[512 + t], red[512 + t + 64]), fmaxf(red[512 + t + 128], red[512 + t + 192]));
      float sc = red[768 + t] + red[768 + t + 64] + red[768 + t + 128] + red[768 + t + 192];
      float sb = red[1024 + t] + red[1024 + t + 64] + red[1024 + t + 128] + red[1024 + t + 192];
      float uu = red[1280 + t] + red[1280 + t + 64] + red[1280 + t + 128] + red[1280 + t + 192];
      float vv = red[1536 + t] + red[1536 + t + 64] + red[1536 + t + 128] + red[1536 + t + 192];
      ma = fmaxf(ma, 1e-20f);
      mb = fmaxf(mb, 1e-20f);
      float ib = 1.0f / (sqrtf(sc + EPSF) + EPSF);
      lsa[t] = 127.0f / ma;
      lsb[t] = 127.0f / mb;
      qsaG[j0 + t] = 127.0f / ma;
      effG[j0 + t] = (mb * (1.0f / 127.0f)) * ib;
      invbnG[j0 + t] = ib;
      rawNA[j0 + t] = sqrtf(sa);
      rawNB[j0 + t] = sqrtf(sb);
      uG[j0 + t] = uu;
      vG[j0 + t] = vv;
    }
  }
  __syncthreads();

  // ---- phase 2: quantize + transpose (int8 LDS) + pack ----
  int cc = t & 63;
  int r4 = t >> 6;
  float sa = lsa[cc];
  float sb = lsb[cc];
  int pS = t >> 2;
  int ch8 = (t & 3) * 8;
  int pgS = j0 + pS;
  int gS = pgS >> 4, laneS = pgS & 15;

  for (int c0 = 0; c0 < C_DIM; c0 += 32) {
    __syncthreads();
#pragma unroll
    for (int v = 0; v < 2; ++v) {
      int q4 = r4 + 4 * v;
      unsigned pa = 0, pb = 0;
#pragma unroll
      for (int uu = 0; uu < 4; ++uu) {
        int c = c0 + q4 * 4 + uu;
        float av = (x[(size_t)c * HW + j0 + cc] - lma[c]) * sa;
        float bv = (s[(size_t)c * HW + j0 + cc] - lmb[c]) * sb;
        int qA = (int)rintf(fminf(fmaxf(av, -127.f), 127.f));
        int qB = (int)rintf(fminf(fmaxf(bv, -127.f), 127.f));
        pa |= ((unsigned)(unsigned char)(signed char)qA) << (8 * uu);
        pb |= ((unsigned)(unsigned char)(signed char)qB) << (8 * uu);
      }
      *(unsigned*)&tA8[cc * 40 + q4 * 4] = pa;
      *(unsigned*)&tB8[cc * 40 + q4 * 4] = pb;
    }
    __syncthreads();
    unsigned long long va = *(const unsigned long long*)&tA8[pS * 40 + ch8];
    *(unsigned long long*)(qa + (size_t)pgS * C_DIM + c0 + ch8) = va;
    unsigned long long vb = *(const unsigned long long*)&tB8[pS * 40 + ch8];
    int k0 = c0 + ch8;
    int sblk = k0 >> 6;
    int quad = (k0 & 63) >> 4;
    int e0 = k0 & 15;
    *(unsigned long long*)(Bp + (size_t)(gS * 12 + sblk) * 1024 + (laneS | (quad << 4)) * 16 + e0) = vb;
  }
}

// ---------------- Kernel G: T_m=4 i8 MFMA GEMM, LDS 3-ring, packed-u32 argmax ---
// 512 blocks = 64 row-groups (256 rows) x 8 col-partitions (partition==XCD, 1.5MB
// Bp slice L2-resident). Wave owns 64 rows (a_res 192 VGPR); per body: 48 MFMA vs
// 12KB LDS read -> MFMA-bound. Argmax state: 1 u32/row = ord-float[31:14] | tag,
// tag = (1023-g)<<4 | (15-m) (monotone; ties -> lowest j). Exact vmcnt: 3 staging
// loads/wave/body are the only in-loop vmem.
__device__ __forceinline__ void gl_lds16(const void* g, void* l) {
  __builtin_amdgcn_global_load_lds((const __attribute__((address_space(1))) uint32_t*)g,
                                   (__attribute__((address_space(3))) uint32_t*)l, 16, 0, 0);
}

__global__ __launch_bounds__(256, 2) void k_gemm_argmax(
    const signed char* __restrict__ qa,
    const signed char* __restrict__ Bp,
    const float* __restrict__ eff,
    unsigned* __restrict__ best) {
  __shared__ signed char ringS[3 * 12288];   // 36 KB
  __shared__ float effL[2048];               // 8 KB
  int t = threadIdx.x;
  int lane = t & 63, w = t >> 6;
  int m = lane & 15, q = lane >> 4;
  int b = blockIdx.x;
  int part = b & 7;                 // partition == XCD (round-robin dispatch)
  int rg = b >> 3;                  // 0..63
  int i0 = rg * 256;
  int g0 = part * GPP;
  int lane16 = lane * 16;
  int sW0 = (3 * w) * 1024 + lane16;

  // ---- A fragments: 4 tiles x 12 ksteps = 192 VGPR ----
  const i32x4* qaV = (const i32x4*)qa;
  i32x4 a_res[4][12];
#pragma unroll
  for (int tm = 0; tm < 4; ++tm) {
    int row = i0 + w * 64 + tm * 16 + m;
#pragma unroll
    for (int s = 0; s < 12; ++s)
      a_res[tm][s] = qaV[(size_t)row * 48 + s * 4 + q];
  }

  // ---- prologue: stage slots 0,1; effL ----
  {
    const signed char* ps = Bp + ((size_t)g0 * 12 + 3 * w) * 1024 + lane16;
#pragma unroll
    for (int gp = 0; gp < 2; ++gp) {
      signed char* dst = ringS + gp * 12288;
      gl_lds16(ps, dst + sW0);
      gl_lds16(ps + 1024, dst + sW0 + 1024);
      gl_lds16(ps + 2048, dst + sW0 + 2048);
      ps += 12288;
    }
  }
  for (int i = t; i < 2048; i += 256) effL[i] = eff[(g0 << 4) + i];
  __syncthreads();   // one-time full drain (vmcnt 0 outstanding after this)

  const signed char* srcW = Bp + ((size_t)(g0 + 2) * 12 + 3 * w) * 1024 + lane16;

  unsigned best16[4][4];
#pragma unroll
  for (int tm = 0; tm < 4; ++tm)
#pragma unroll
    for (int r = 0; r < 4; ++r) best16[tm][r] = 0u;

  unsigned tag = ((unsigned)(1023 - g0) << 4) | (unsigned)(15 - m);
  int effIdx = m;

#define BODY(SLOT, VMSTR, DOSTAGE)                                                 \
  {                                                                                \
    asm volatile(VMSTR ::: "memory");                                              \
    __builtin_amdgcn_s_barrier();                                                  \
    const signed char* rb = ringS + (SLOT) * 12288;                                \
    if (DOSTAGE) {                                                                 \
      signed char* dst = ringS + (((SLOT) + 2) % 3) * 12288;                       \
      gl_lds16(srcW, dst + sW0);                                                   \
      gl_lds16(srcW + 1024, dst + sW0 + 1024);                                     \
      gl_lds16(srcW + 2048, dst + sW0 + 2048);                                     \
      srcW += 12288;                                                               \
    }                                                                              \
    i32x4 acc0 = {0,0,0,0}, acc1 = {0,0,0,0}, acc2 = {0,0,0,0}, acc3 = {0,0,0,0};  \
    i32x4 fa = *(const i32x4*)(rb + lane16);                                       \
    i32x4 fb = *(const i32x4*)(rb + 1024 + lane16);                                \
    _Pragma("unroll")                                                              \
    for (int s = 0; s < 12; ++s) {                                                 \
      i32x4 fn = fb;                                                               \
      if (s < 10) fn = *(const i32x4*)(rb + (s + 2) * 1024 + lane16);              \
      acc0 = __builtin_amdgcn_mfma_i32_16x16x64_i8(a_res[0][s], fa, acc0, 0, 0, 0); \
      acc1 = __builtin_amdgcn_mfma_i32_16x16x64_i8(a_res[1][s], fa, acc1, 0, 0, 0); \
      acc2 = __builtin_amdgcn_mfma_i32_16x16x64_i8(a_res[2][s], fa, acc2, 0, 0, 0); \
      acc3 = __builtin_amdgcn_mfma_i32_16x16x64_i8(a_res[3][s], fa, acc3, 0, 0, 0); \
      fa = fb; fb = fn;                                                            \
    }                                                                              \
    float ecur = effL[effIdx];                                                     \
    _Pragma("unroll")                                                              \
    for (int r = 0; r < 4; ++r) {                                                  \
      float v0 = (float)acc0[r] * ecur;                                            \
      float v1 = (float)acc1[r] * ecur;                                            \
      float v2 = (float)acc2[r] * ecur;                                            \
      float v3 = (float)acc3[r] * ecur;                                            \
      unsigned u0 = __float_as_uint(v0); u0 = (u0 & 0x80000000u) ? ~u0 : (u0 | 0x80000000u); \
      unsigned u1 = __float_as_uint(v1); u1 = (u1 & 0x80000000u) ? ~u1 : (u1 | 0x80000000u); \
      unsigned u2 = __float_as_uint(v2); u2 = (u2 & 0x80000000u) ? ~u2 : (u2 | 0x80000000u); \
      unsigned u3 = __float_as_uint(v3); u3 = (u3 & 0x80000000u) ? ~u3 : (u3 | 0x80000000u); \
      u0 = (u0 & 0xFFFFC000u) | tag;                                               \
      u1 = (u1 & 0xFFFFC000u) | tag;                                               \
      u2 = (u2 & 0xFFFFC000u) | tag;                                               \
      u3 = (u3 & 0xFFFFC000u) | tag;                                               \
      if (u0 > best16[0][r]) best16[0][r] = u0;                                    \
      if (u1 > best16[1][r]) best16[1][r] = u1;                                    \
      if (u2 > best16[2][r]) best16[2][r] = u2;                                    \
      if (u3 > best16[3][r]) best16[3][r] = u3;                                    \
    }                                                                              \
    tag -= 16u;                                                                    \
    effIdx += 16;                                                                  \
  }

  for (int it = 0; it < 42; ++it) {       // bodies 0..125, stage slots 2..127
    BODY(0, "s_waitcnt vmcnt(3)", 1)
    BODY(1, "s_waitcnt vmcnt(3)", 1)
    BODY(2, "s_waitcnt vmcnt(3)", 1)
  }
  BODY(0, "s_waitcnt vmcnt(3)", 0)        // body 126
  BODY(1, "s_waitcnt vmcnt(0)", 0)        // body 127
#undef BODY

  // ---- reduce over 16 column-lanes (umax is tie-correct), one atomic per row ----
#pragma unroll
  for (int tm = 0; tm < 4; ++tm) {
#pragma unroll
    for (int r = 0; r < 4; ++r) {
      unsigned bv = best16[tm][r];
#pragma unroll
      for (int off = 1; off < 16; off <<= 1) {
        unsigned ov = __shfl_xor(bv, off, 64);
        if (ov > bv) bv = ov;
      }
      if (m == 0) {
        int i = i0 + w * 64 + tm * 16 + q * 4 + r;
        atomicMax(&best[i], bv);
      }
    }
  }
}

// ---------------- Kernel D: final loss via analytic dot reconstruction ----------
__global__ __launch_bounds__(256) void k_loss2(const float* __restrict__ meanA,
                                               const float* __restrict__ meanB,
                                               const unsigned* __restrict__ best,
                                               const float* __restrict__ rawNA,
                                               const float* __restrict__ rawNB,
                                               const float* __restrict__ invbn,
                                               const float* __restrict__ qsa,
                                               const float* __restrict__ u,
                                               const float* __restrict__ v,
                                               float* __restrict__ out) {
  __shared__ float red[256];
  int t = threadIdx.x;
  float wp = 0.f;
  for (int c = t; c < C_DIM; c += 256) wp += meanA[c] * meanB[c];
  red[t] = wp;
  __syncthreads();
  for (int o = 128; o > 0; o >>= 1) {
    if (t < o) red[t] += red[t + o];
    __syncthreads();
  }
  float wdot = red[0];
  __syncthreads();

  int i = blockIdx.x * 256 + t;
  unsigned pk = best[i];
  int tagv = (int)(pk & 0x3FFFu);
  int g = 1023 - (tagv >> 4);
  int mm = 15 - (tagv & 0xF);
  int j = g * 16 + mm;
  unsigned ou = pk & 0xFFFFC000u;
  unsigned fu = (ou & 0x80000000u) ? (ou & 0x7FFFFFFFu) : ~ou;
  float bv = __uint_as_float(fu);
  float dotcc = bv / (invbn[j] * qsa[i]);
  float dot = dotcc + u[i] + v[j] + wdot;
  float cs = dot / ((rawNA[i] + EPSF) * (rawNB[j] + EPSF));
  red[t] = (1.0f - cs) * (1.0f / HW);
  __syncthreads();
  for (int o = 128; o > 0; o >>= 1) {
    if (t < o) red[t] += red[t + o];
    __syncthreads();
  }
  if (t == 0) atomicAdd(out, red[0]);
}

// ---------------- Launch ----------------
extern "C" void kernel_launch(void* const* d_in, const int* in_sizes, int n_in,
                              void* d_out, int out_size, void* d_ws, size_t ws_size,
                              hipStream_t stream) {
  const float* x = (const float*)d_in[0];
  const float* s = (const float*)d_in[1];
  char* ws = (char*)d_ws;
  float* meanA = (float*)(ws + 0);
  float* meanB = (float*)(ws + 4096);
  float* rawNA = (float*)(ws + 8192);
  float* rawNB = (float*)(ws + 73728);
  float* eff   = (float*)(ws + 139264);
  float* qsa   = (float*)(ws + 204800);
  float* invbn = (float*)(ws + 335872);
  float* u     = (float*)(ws + 401408);
  float* v     = (float*)(ws + 466944);
  unsigned* best = (unsigned*)(ws + 532480);
  signed char* qa = (signed char*)(ws + 663552);
  signed char* Bp = (signed char*)(ws + 663552 + 12582912);
  float* out = (float*)d_out;

  hipMemsetAsync(best, 0, HW * sizeof(unsigned), stream);
  hipMemsetAsync(out, 0, sizeof(float), stream);
  k_means<<<2 * C_DIM, 256, 0, stream>>>(x, s, meanA, meanB);
  k_prepq<<<HW / 64, 256, 0, stream>>>(x, s, meanA, meanB, qsa, eff, invbn, rawNA, rawNB, u, v, qa, Bp);
  k_gemm_argmax<<<512, 256, 0, stream>>>(qa, Bp, eff, best);
  k_loss2<<<HW / 256, 256, 0, stream>>>(meanA, meanB, best, rawNA, rawNB, invbn, qsa, u, v, out);
}

// Round 9
// 356.346 us; speedup vs baseline: 1.4274x; 1.4274x over previous
//
#include <hip/hip_runtime.h>
#include <hip/hip_bf16.h>
#include <stdint.h>

#define C_DIM 768
#define HW 16384
#define EPSF 1e-8f
#define GPQ 256            // groups (16 cols) per quarter

typedef __attribute__((ext_vector_type(4))) int i32x4;

// ---------------- Kernel A: per-channel means over spatial dim ----------------
__global__ __launch_bounds__(256) void k_means(const float* __restrict__ x,
                                               const float* __restrict__ s,
                                               float* __restrict__ meanA,
                                               float* __restrict__ meanB) {
  int ch = blockIdx.x;
  const float* src = (ch < C_DIM) ? (x + (size_t)ch * HW) : (s + (size_t)(ch - C_DIM) * HW);
  const float4* src4 = (const float4*)src;
  int t = threadIdx.x;
  float acc = 0.f;
  for (int i = t; i < HW / 4; i += 256) {
    float4 v = src4[i];
    acc += v.x + v.y + v.z + v.w;
  }
  __shared__ float red[256];
  red[t] = acc;
  __syncthreads();
  for (int o = 128; o > 0; o >>= 1) {
    if (t < o) red[t] += red[t + o];
    __syncthreads();
  }
  if (t == 0) {
    float m = red[0] * (1.0f / HW);
    if (ch < C_DIM) meanA[ch] = m; else meanB[ch - C_DIM] = m;
  }
}

// ---------------- Kernel S: per-position stats (512 blocks x 32 pos) ----------
__global__ __launch_bounds__(256) void k_stats(const float* __restrict__ x,
                                               const float* __restrict__ s,
                                               const float* __restrict__ meanA,
                                               const float* __restrict__ meanB,
                                               float* __restrict__ qsaG,
                                               float* __restrict__ qsbG,
                                               float* __restrict__ effG,
                                               float* __restrict__ invbnG,
                                               float* __restrict__ rawNA,
                                               float* __restrict__ rawNB,
                                               float* __restrict__ uG,
                                               float* __restrict__ vG) {
  __shared__ float lma[C_DIM], lmb[C_DIM];
  __shared__ float red[7 * 256];
  int t = threadIdx.x;
  int p0 = blockIdx.x * 32;
  for (int c = t; c < C_DIM; c += 256) { lma[c] = meanA[c]; lmb[c] = meanB[c]; }
  __syncthreads();
  int pl = t & 31, cl = t >> 5;      // 8 c-lanes per position
  int p = p0 + pl;
  float maxa = 0.f, ssaR = 0.f, maxb = 0.f, ssbC = 0.f, ssbR = 0.f, uacc = 0.f, vacc = 0.f;
  for (int c = cl; c < C_DIM; c += 8) {
    float av = x[(size_t)c * HW + p];
    float bv = s[(size_t)c * HW + p];
    float ac = av - lma[c];
    float bc = bv - lmb[c];
    maxa = fmaxf(maxa, fabsf(ac));
    maxb = fmaxf(maxb, fabsf(bc));
    ssaR += av * av;
    ssbC += bc * bc;
    ssbR += bv * bv;
    uacc += ac * lmb[c];
    vacc += bc * lma[c];
  }
  red[t] = maxa; red[256 + t] = ssaR; red[512 + t] = maxb;
  red[768 + t] = ssbC; red[1024 + t] = ssbR; red[1280 + t] = uacc; red[1536 + t] = vacc;
  __syncthreads();
  if (t < 32) {
    float ma = 0.f, sa = 0.f, mb = 0.f, sc = 0.f, sb = 0.f, uu = 0.f, vv = 0.f;
#pragma unroll
    for (int k = 0; k < 8; ++k) {
      int idx = t + k * 32;
      ma = fmaxf(ma, red[idx]);
      sa += red[256 + idx];
      mb = fmaxf(mb, red[512 + idx]);
      sc += red[768 + idx];
      sb += red[1024 + idx];
      uu += red[1280 + idx];
      vv += red[1536 + idx];
    }
    ma = fmaxf(ma, 1e-20f);
    mb = fmaxf(mb, 1e-20f);
    float ib = 1.0f / (sqrtf(sc + EPSF) + EPSF);
    qsaG[p0 + t] = 127.0f / ma;
    qsbG[p0 + t] = 127.0f / mb;
    effG[p0 + t] = (mb * (1.0f / 127.0f)) * ib;
    invbnG[p0 + t] = ib;
    rawNA[p0 + t] = sqrtf(sa);
    rawNB[p0 + t] = sqrtf(sb);
    uG[p0 + t] = uu;
    vG[p0 + t] = vv;
  }
}

// ---------------- Kernel Q: quantize + int8-LDS transpose + pack ----------------
// 512 blocks x 32 positions; 12 iters of 64-channel tiles; 8B vector stores.
__global__ __launch_bounds__(256) void k_quant(const float* __restrict__ x,
                                               const float* __restrict__ s,
                                               const float* __restrict__ meanA,
                                               const float* __restrict__ meanB,
                                               const float* __restrict__ qsa,
                                               const float* __restrict__ qsb,
                                               signed char* __restrict__ qa,
                                               signed char* __restrict__ Bp) {
  __shared__ float lma[C_DIM], lmb[C_DIM];
  __shared__ signed char tA8[32 * 72];
  __shared__ signed char tB8[32 * 72];
  int t = threadIdx.x;
  int j0 = blockIdx.x * 32;
  for (int c = t; c < C_DIM; c += 256) { lma[c] = meanA[c]; lmb[c] = meanB[c]; }

  int cc = t & 31;                 // position (load side)
  int r8 = t >> 5;                 // c-quad base (load side), 8 slots
  float sa = qsa[j0 + cc];
  float sb = qsb[j0 + cc];
  int pS = t >> 3;                 // row (store side) 0..31
  int ch8 = (t & 7) * 8;           // 8B chunk within 64B row
  int pgS = j0 + pS;
  int gS = pgS >> 4, laneS = pgS & 15;

  for (int c0 = 0; c0 < C_DIM; c0 += 64) {
    __syncthreads();
#pragma unroll
    for (int v = 0; v < 2; ++v) {
      int q4 = r8 + 8 * v;        // 0..15: which 4-channel pack within 64-c tile
      unsigned pa = 0, pb = 0;
#pragma unroll
      for (int uu = 0; uu < 4; ++uu) {
        int c = c0 + q4 * 4 + uu;
        float av = (x[(size_t)c * HW + j0 + cc] - lma[c]) * sa;
        float bv = (s[(size_t)c * HW + j0 + cc] - lmb[c]) * sb;
        int qA = (int)rintf(fminf(fmaxf(av, -127.f), 127.f));
        int qB = (int)rintf(fminf(fmaxf(bv, -127.f), 127.f));
        pa |= ((unsigned)(unsigned char)(signed char)qA) << (8 * uu);
        pb |= ((unsigned)(unsigned char)(signed char)qB) << (8 * uu);
      }
      *(unsigned*)&tA8[cc * 72 + q4 * 4] = pa;
      *(unsigned*)&tB8[cc * 72 + q4 * 4] = pb;
    }
    __syncthreads();
    unsigned long long va = *(const unsigned long long*)&tA8[pS * 72 + ch8];
    *(unsigned long long*)(qa + (size_t)pgS * C_DIM + c0 + ch8) = va;
    unsigned long long vb = *(const unsigned long long*)&tB8[pS * 72 + ch8];
    int k0 = c0 + ch8;
    int sblk = k0 >> 6;
    int quad = (k0 & 63) >> 4;
    int e0 = k0 & 15;
    *(unsigned long long*)(Bp + (size_t)(gS * 12 + sblk) * 1024 + (laneS | (quad << 4)) * 16 + e0) = vb;
  }
}

// ---------------- Kernel G: i8 MFMA GEMM, LDS 4-ring, exact vmcnt (R6 verbatim) --
// 512 blocks (2/CU, 2 waves/SIMD). xcd=b&7, quarter=xcd>>1 (3MB Bp quarter,
// L2-resident). Block owns 128 rows; wave owns 32 (T_m=2, a_res=96 VGPR). B groups
// (12KB) stream through a 4-deep LDS ring via global_load_lds (3 instrs/wave/body
// = only in-loop vmem -> s_waitcnt vmcnt(6) exact, prefetch distance 3 bodies).
__device__ __forceinline__ void gl_lds16(const void* g, void* l) {
  __builtin_amdgcn_global_load_lds((const __attribute__((address_space(1))) uint32_t*)g,
                                   (__attribute__((address_space(3))) uint32_t*)l, 16, 0, 0);
}

__global__ __launch_bounds__(256, 2) void k_gemm_argmax(
    const signed char* __restrict__ qa,
    const signed char* __restrict__ Bp,
    const float* __restrict__ eff,
    unsigned long long* __restrict__ best) {
  __shared__ signed char ringS[4 * 12288];   // 48 KB
  __shared__ float effL[4096];               // 16 KB
  int t = threadIdx.x;
  int lane = t & 63, w = t >> 6;
  int m = lane & 15, q = lane >> 4;
  int b = blockIdx.x;
  int xcd = b & 7;
  int bq = xcd >> 1;
  int rg = (b >> 3) | ((xcd & 1) << 6);      // 0..127
  int i0 = rg * 128;
  int g0 = bq * GPQ;
  int lane16 = lane * 16;
  int sW0 = (3 * w) * 1024 + lane16;

  const i32x4* qaV = (const i32x4*)qa;
  i32x4 a_res[2][12];
#pragma unroll
  for (int tm = 0; tm < 2; ++tm) {
    int row = i0 + w * 32 + tm * 16 + m;
#pragma unroll
    for (int s = 0; s < 12; ++s)
      a_res[tm][s] = qaV[(size_t)row * 48 + s * 4 + q];
  }

  {
    const signed char* ps = Bp + ((size_t)g0 * 12 + 3 * w) * 1024 + lane16;
#pragma unroll
    for (int gp = 0; gp < 3; ++gp) {
      signed char* dst = ringS + gp * 12288;
      gl_lds16(ps, dst + sW0);
      gl_lds16(ps + 1024, dst + sW0 + 1024);
      gl_lds16(ps + 2048, dst + sW0 + 2048);
      ps += 12288;
    }
  }
  for (int i = t; i < 4096; i += 256) effL[i] = eff[(g0 << 4) + i];
  __syncthreads();   // one-time full drain

  const signed char* srcW = Bp + ((size_t)(g0 + 3) * 12 + 3 * w) * 1024 + lane16;

  float bestv[2][4];
  int bestj[2][4];
#pragma unroll
  for (int tm = 0; tm < 2; ++tm)
#pragma unroll
    for (int r = 0; r < 4; ++r) { bestv[tm][r] = -3.0e38f; bestj[tm][r] = 0x7FFFFFFF; }

  int effOff = m;
  int jj = (g0 << 4) + m;

#define BODY(RB, VMSTR, DOSTAGE)                                                   \
  {                                                                                \
    asm volatile(VMSTR ::: "memory");                                              \
    __builtin_amdgcn_s_barrier();                                                  \
    const signed char* rb = ringS + (RB) * 12288;                                  \
    i32x4 f[12];                                                                   \
    _Pragma("unroll")                                                              \
    for (int s = 0; s < 12; ++s)                                                   \
      f[s] = *(const i32x4*)(rb + s * 1024 + lane16);                              \
    float ecur = effL[effOff];                                                     \
    i32x4 acc0 = {0, 0, 0, 0}, acc1 = {0, 0, 0, 0};                                \
    _Pragma("unroll")                                                              \
    for (int s = 0; s < 12; ++s) {                                                 \
      acc0 = __builtin_amdgcn_mfma_i32_16x16x64_i8(a_res[0][s], f[s], acc0, 0, 0, 0); \
      acc1 = __builtin_amdgcn_mfma_i32_16x16x64_i8(a_res[1][s], f[s], acc1, 0, 0, 0); \
    }                                                                              \
    if (DOSTAGE) {                                                                 \
      signed char* dst = ringS + (((RB) + 3) & 3) * 12288;                         \
      gl_lds16(srcW, dst + sW0);                                                   \
      gl_lds16(srcW + 1024, dst + sW0 + 1024);                                     \
      gl_lds16(srcW + 2048, dst + sW0 + 2048);                                     \
      srcW += 12288;                                                               \
    }                                                                              \
    _Pragma("unroll")                                                              \
    for (int r = 0; r < 4; ++r) {                                                  \
      float v0 = (float)acc0[r] * ecur;                                            \
      float v1 = (float)acc1[r] * ecur;                                            \
      if (v0 > bestv[0][r]) { bestv[0][r] = v0; bestj[0][r] = jj; }                \
      if (v1 > bestv[1][r]) { bestv[1][r] = v1; bestj[1][r] = jj; }                \
    }                                                                              \
    effOff += 16;                                                                  \
    jj += 16;                                                                      \
  }

  for (int mi = 0; mi < 63; ++mi) {
    BODY(0, "s_waitcnt vmcnt(6)", 1)
    BODY(1, "s_waitcnt vmcnt(6)", 1)
    BODY(2, "s_waitcnt vmcnt(6)", 1)
    BODY(3, "s_waitcnt vmcnt(6)", 1)
  }
  BODY(0, "s_waitcnt vmcnt(6)", 1)   // gl=252, stages group 255
  BODY(1, "s_waitcnt vmcnt(6)", 0)   // gl=253
  BODY(2, "s_waitcnt vmcnt(3)", 0)   // gl=254
  BODY(3, "s_waitcnt vmcnt(0)", 0)   // gl=255
#undef BODY

#pragma unroll
  for (int tm = 0; tm < 2; ++tm) {
#pragma unroll
    for (int r = 0; r < 4; ++r) {
      float bv = bestv[tm][r];
      int bj = bestj[tm][r];
#pragma unroll
      for (int off = 1; off < 16; off <<= 1) {
        float ov = __shfl_xor(bv, off, 64);
        int oj = __shfl_xor(bj, off, 64);
        if (ov > bv || (ov == bv && oj < bj)) { bv = ov; bj = oj; }
      }
      if (m == 0) {
        int i = i0 + w * 32 + tm * 16 + q * 4 + r;
        unsigned key = __float_as_uint(bv);
        key = (key & 0x80000000u) ? ~key : (key | 0x80000000u);
        unsigned long long packed =
            ((unsigned long long)key << 32) | (unsigned long long)(0xFFFFFFFFu - (unsigned)bj);
        atomicMax(&best[i], packed);
      }
    }
  }
}

// ---------------- Kernel D: final loss via analytic dot reconstruction ----------
__global__ __launch_bounds__(256) void k_loss2(const float* __restrict__ meanA,
                                               const float* __restrict__ meanB,
                                               const unsigned long long* __restrict__ best,
                                               const float* __restrict__ rawNA,
                                               const float* __restrict__ rawNB,
                                               const float* __restrict__ invbn,
                                               const float* __restrict__ qsa,
                                               const float* __restrict__ u,
                                               const float* __restrict__ v,
                                               float* __restrict__ out) {
  __shared__ float red[256];
  int t = threadIdx.x;
  float wp = 0.f;
  for (int c = t; c < C_DIM; c += 256) wp += meanA[c] * meanB[c];
  red[t] = wp;
  __syncthreads();
  for (int o = 128; o > 0; o >>= 1) {
    if (t < o) red[t] += red[t + o];
    __syncthreads();
  }
  float wdot = red[0];
  __syncthreads();

  int i = blockIdx.x * 256 + t;
  unsigned long long pk = best[i];
  unsigned key = (unsigned)(pk >> 32);
  unsigned fb = (key & 0x80000000u) ? (key & 0x7FFFFFFFu) : ~key;
  float bv = __uint_as_float(fb);
  int j = (int)(0xFFFFFFFFu - (unsigned)(pk & 0xFFFFFFFFull));
  float dotcc = bv / (invbn[j] * qsa[i]);
  float dot = dotcc + u[i] + v[j] + wdot;
  float cs = dot / ((rawNA[i] + EPSF) * (rawNB[j] + EPSF));
  red[t] = (1.0f - cs) * (1.0f / HW);
  __syncthreads();
  for (int o = 128; o > 0; o >>= 1) {
    if (t < o) red[t] += red[t + o];
    __syncthreads();
  }
  if (t == 0) atomicAdd(out, red[0]);
}

// ---------------- Launch ----------------
extern "C" void kernel_launch(void* const* d_in, const int* in_sizes, int n_in,
                              void* d_out, int out_size, void* d_ws, size_t ws_size,
                              hipStream_t stream) {
  const float* x = (const float*)d_in[0];
  const float* s = (const float*)d_in[1];
  char* ws = (char*)d_ws;
  float* meanA = (float*)(ws + 0);
  float* meanB = (float*)(ws + 4096);
  float* rawNA = (float*)(ws + 8192);
  float* rawNB = (float*)(ws + 73728);
  float* eff   = (float*)(ws + 139264);
  float* qsa   = (float*)(ws + 204800);
  float* qsb   = (float*)(ws + 270336);
  float* invbn = (float*)(ws + 335872);
  float* u     = (float*)(ws + 401408);
  float* v     = (float*)(ws + 466944);
  unsigned long long* best = (unsigned long long*)(ws + 532480);
  signed char* qa = (signed char*)(ws + 663552);
  signed char* Bp = (signed char*)(ws + 663552 + 12582912);
  float* out = (float*)d_out;

  hipMemsetAsync(best, 0, HW * sizeof(unsigned long long), stream);
  hipMemsetAsync(out, 0, sizeof(float), stream);
  k_means<<<2 * C_DIM, 256, 0, stream>>>(x, s, meanA, meanB);
  k_stats<<<HW / 32, 256, 0, stream>>>(x, s, meanA, meanB, qsa, qsb, eff, invbn, rawNA, rawNB, u, v);
  k_quant<<<HW / 32, 256, 0, stream>>>(x, s, meanA, meanB, qsa, qsb, qa, Bp);
  k_gemm_argmax<<<512, 256, 0, stream>>>(qa, Bp, eff, best);
  k_loss2<<<HW / 256, 256, 0, stream>>>(meanA, meanB, best, rawNA, rawNB, invbn, qsa, u, v, out);
}